// Round 5
// baseline (1261.119 us; speedup 1.0000x reference)
//
#include <hip/hip_runtime.h>
#include <hip/hip_bf16.h>

// GraphUnet forward.
//  - Down path precision strategy (feeds both top-k pools):
//    Big A-GEMMs (M=N=4096,K=4096 x DIM) via Ozaki-style exact-int8 on the
//    i8 matrix core:
//      A in [0,1) -> 4 unsigned 7-bit planes (exact f32 bit-slices).
//      Y -> 4 signed 7-bit planes vs power-of-2 scale M (|y_j| <= 64).
//      i8 MFMA accumulates in i32 EXACTLY (max 4096*127*64 ~ 3.3e7 << 2^31).
//      R11: gridDim.z = 4 = A-plane ip; each block loops jp = 0..(3-ip) full
//      K-sweeps (pairs i+j<=3), writing C-slice CBASE[ip]+jp. A-plane is
//      HBM-streamed once (concurrent j=0 sweeps) and L3-hit for j>=1; all
//      B-planes (5.2MB) stay L2-resident. Slice->s grouping {0},{1,4},
//      {2,5,7},{3,6,8,9} (= R10 reasm2) -> bit-identical integer sums.
//      T = M*2^-13*sum_s 2^-7s C_s, rel err ~1e-8 (f64-grade ranking).
//    R10 post-mortem: 2-phase dbuf REGRESSED (93->111us, MfmaUtil 27.5->23):
//    64KB LDS cut resident-block headroom; latency on this structure is
//    hidden by TLP, not source-level pipelining (matches m99/m100/m132).
//    ozaki kernel is back to the R9-verified single-buffer 2-barrier form:
//    BM=BN=128 (N pad 384), BK=128, 4 waves 2x2, wave 64x64, i8 MFMA
//    16x16x64, gload16 + XOR chunk swizzle -> 0 bank conflicts (R9-verified).
//    Small K=320 feature GEMMs (+bias+relu) stay f64 MFMA (R7 DMA pipeline).
//  - Up path big A-GEMMs (bf16): mfma2_k, ozaki structure clone (BM=BN=128,
//    wave 64x64, BK=64, gload16 + XOR swizzle), R11: single-buffer (dbuf
//    reverted here too).
//  - top_k = bitonic sort, 3-dispatch split (R9).
//  - A1 = A[idx][:,idx] never materialized: A1@Y = gather_idx(A @ scatter_idx(Y)).

constexpr int NN  = 4096;
constexpr int DIM = 320;
constexpr int KP0 = 3686;
constexpr int KP1 = 2580;

typedef __attribute__((ext_vector_type(8))) short short8_t;
typedef __attribute__((ext_vector_type(4))) float floatx4;
typedef __attribute__((ext_vector_type(4))) double double4v;
typedef __attribute__((ext_vector_type(4))) int int4v;

// 16B global->LDS DMA. LDS dest is wave-uniform base; HW adds lane*16.
__device__ __forceinline__ void gload16(const void* g, void* l) {
  __builtin_amdgcn_global_load_lds(
      (__attribute__((address_space(1))) void*)g,
      (__attribute__((address_space(3))) void*)l, 16, 0, 0);
}

// ---------------- f64 MFMA GEMM: C = A @ B (+bias, relu) ---------------------
// Small K=320 feature GEMMs. A: M x K f64 row-major (rows optionally
// gathered). B: K x N f64 row-major. C: M x N f64. Tiles 64x32, BK=32;
// 4 waves (2x2), wave = 32m x 16n. 2-phase dbuf, gload16 + XOR swizzle (R7).
template<typename TA, int EPI, bool AGATHER>
__global__ __launch_bounds__(256) void dmfma_k(
    const TA* __restrict__ Ag, const double* __restrict__ Bg, double* __restrict__ Cg,
    const float* __restrict__ bias, const int* __restrict__ aidx,
    int M, int N, int klen, int lda, int ldb, int ldc)
{
  constexpr int BM = 64, BN = 32, BK = 32;
  constexpr bool AF32 = (sizeof(TA) == 4);
  constexpr int ACPR = AF32 ? 8 : 16;       // A 16B-chunks per LDS row
  constexpr int ACPT = (BM * ACPR) / 256;   // A chunks per thread
  __shared__ __align__(16) TA     As[2][BM * BK];
  __shared__ __align__(16) double Bs[2][BK * BN];
  const int tid  = threadIdx.x;
  const int wave = tid >> 6, lane = tid & 63;
  const int wm = wave >> 1, wn = wave & 1;
  const int m0 = blockIdx.y * BM, n0 = blockIdx.x * BN;
  const int ml = lane & 15, kl = lane >> 4;
  const int kof = blockIdx.z * klen;
  Cg += (size_t)blockIdx.z * M * ldc;

  const TA* aptr[ACPT];
#pragma unroll
  for (int i = 0; i < ACPT; ++i) {
    int ch = (wave * ACPT + i) * 64 + lane;
    int r = ch / ACPR, c = ch % ACPR;
    int row = m0 + r; if (row >= M) row = M - 1;
    int ar = AGATHER ? aidx[row] : row;
    int csrc = c ^ (r & (ACPR - 1));
    aptr[i] = Ag + (size_t)ar * lda + csrc * (16 / (int)sizeof(TA));
  }
  const double* bptr[2];
#pragma unroll
  for (int i = 0; i < 2; ++i) {
    int ch = (wave * 2 + i) * 64 + lane;
    int r = ch >> 4, c = ch & 15;
    int csrc = c ^ ((r & 3) << 2);
    bptr[i] = Bg + (size_t)r * ldb + n0 + csrc * 2;
  }

  auto stage = [&](int buf, int k0) {
#pragma unroll
    for (int i = 0; i < ACPT; ++i)
      gload16(aptr[i] + k0, &As[buf][(wave * ACPT + i) * (1024 / (int)sizeof(TA))]);
#pragma unroll
    for (int i = 0; i < 2; ++i)
      gload16(bptr[i] + (size_t)k0 * ldb, &Bs[buf][(wave * 2 + i) * 128]);
  };

  double4v acc[2];
#pragma unroll
  for (int i = 0; i < 2; ++i)
#pragma unroll
    for (int r = 0; r < 4; ++r) acc[i][r] = 0.0;

  const int nB = wn * 16 + ml;
  const int bconst = ((((nB >> 1) ^ (kl << 2)) << 1) | (nB & 1));
  const int mA = wm * 32 + ml;
  const int m7 = ml & 7;
  const int abase_f32 = mA * 32 + kl;
  const int abase_f64 = mA * 32 + (kl & 1);

  stage(0, kof);
  __syncthreads();
  int cur = 0;
  const int nt = klen / BK;
  for (int t = 0; t < nt; ++t) {
    if (t + 1 < nt) stage(cur ^ 1, kof + (t + 1) * BK);
    const TA*     Af = As[cur];
    const double* Bf = Bs[cur];
#pragma unroll
    for (int ks = 0; ks < BK; ks += 4) {
      double b = Bf[bconst + (ks + kl) * 32];
      double a0, a1;
      if constexpr (AF32) {
        int ia = abase_f32 + (((ks >> 2) ^ m7) << 2);
        a0 = (double)Af[ia];
        a1 = (double)Af[ia + 512];
      } else {
        int ia = abase_f64 + ((((ks + kl) >> 1) ^ ml) << 1);
        a0 = (double)Af[ia];
        a1 = (double)Af[ia + 512];
      }
      acc[0] = __builtin_amdgcn_mfma_f64_16x16x4f64(a0, b, acc[0], 0, 0, 0);
      acc[1] = __builtin_amdgcn_mfma_f64_16x16x4f64(a1, b, acc[1], 0, 0, 0);
    }
    __syncthreads();
    cur ^= 1;
  }

  const int n = n0 + wn * 16 + ml;
#pragma unroll
  for (int mi = 0; mi < 2; ++mi)
#pragma unroll
    for (int r = 0; r < 4; ++r) {
      int m = m0 + wm * 32 + mi * 16 + kl * 4 + r;
      if (m >= M || n >= N) continue;
      double v = acc[mi][r];
      if (EPI == 1) { v += (double)bias[n]; v = v > 0.0 ? v : 0.0; }
      Cg[(size_t)m * ldc + n] = v;
    }
}

// ---------------- Ozaki int8 machinery --------------------------------------
// A slice planes: A = sum_i a_i * 2^-7(i+1) + eps, a_i in [0,127], eps < 2^-28.
__global__ __launch_bounds__(256) void sliceA_k(
    const float* __restrict__ A, signed char* __restrict__ P)
{
  const size_t nn = (size_t)NN * NN;
  size_t g = ((size_t)blockIdx.x * 256 + threadIdx.x) * 4;
  if (g >= nn) return;
  float4 v = *(const float4*)(A + g);
  float fv[4] = {v.x, v.y, v.z, v.w};
  signed char out[4][4];
#pragma unroll
  for (int e = 0; e < 4; ++e) {
    float t = fv[e];
#pragma unroll
    for (int i = 0; i < 4; ++i) {
      t *= 128.f;
      int a = (int)t;              // floor (t >= 0), exact bit-slice
      t -= (float)a;
      out[i][e] = (signed char)a;
    }
  }
#pragma unroll
  for (int i = 0; i < 4; ++i)
    *(char4*)(P + (size_t)i * nn + g) =
        make_char4(out[i][0], out[i][1], out[i][2], out[i][3]);
}

// max |x| over array -> atomicMax on f64 bit pattern (nonneg -> monotone in ull)
template<typename T>
__global__ __launch_bounds__(256) void maxabs_k(
    const T* __restrict__ x, unsigned long long* __restrict__ out, int n)
{
  double m = 0.0;
  for (int i = blockIdx.x * 256 + threadIdx.x; i < n; i += gridDim.x * 256)
    m = fmax(m, fabs((double)x[i]));
  for (int o = 32; o > 0; o >>= 1) m = fmax(m, __shfl_down(m, o, 64));
  if ((threadIdx.x & 63) == 0 && m > 0.0)
    atomicMax(out, (unsigned long long)__double_as_longlong(m));
}

__device__ __forceinline__ double oz_scale(const unsigned long long* Msc) {
  double mx = __longlong_as_double((long long)*Msc);
  if (!(mx > 0.0)) return 1.0;
  int e; frexp(mx, &e);
  return ldexp(1.0, e);             // power of 2 >= mx
}

// Y [NN][DIM] (f32 or f64) -> 4 signed 7-bit planes, TRANSPOSED: Bp[4][DIM][NN].
// y = M*(y0*2^-6 + y1*2^-13 + y2*2^-20 + y3*2^-27) + eps, |eps| <= M*2^-28.
template<typename TIN>
__global__ __launch_bounds__(256) void sliceYT_k(
    const TIN* __restrict__ Y, const unsigned long long* __restrict__ Msc,
    signed char* __restrict__ Bp)
{
  __shared__ double s[64][65];
  const int c0 = blockIdx.x * 64;    // feature col
  const int r0 = blockIdx.y * 64;    // node row
  const int tid = threadIdx.x;
  const int c = tid & 63, rr = tid >> 6;
#pragma unroll
  for (int i = 0; i < 64; i += 4)
    s[rr + i][c] = (double)Y[(size_t)(r0 + rr + i) * DIM + c0 + c];
  __syncthreads();
  const double inv = 1.0 / oz_scale(Msc);   // exact (power of 2)
  const int r2 = tid & 63, cc = tid >> 6;
  const size_t ps = (size_t)DIM * NN;
  for (int i = 0; i < 64; i += 4) {
    int c2 = cc + i;
    double q = s[r2][c2] * inv;               // |q| <= 1, exact
    int y0 = __double2int_rn(q * 64.0);  double r = q * 64.0  - y0;
    int y1 = __double2int_rn(r * 128.0);        r = r * 128.0 - y1;
    int y2 = __double2int_rn(r * 128.0);        r = r * 128.0 - y2;
    int y3 = __double2int_rn(r * 128.0);
    size_t o = (size_t)(c0 + c2) * NN + (r0 + r2);
    Bp[o]          = (signed char)y0;
    Bp[ps + o]     = (signed char)y1;
    Bp[2 * ps + o] = (signed char)y2;
    Bp[3 * ps + o] = (signed char)y3;
  }
}

// R11 i8 GEMM: blockIdx.z = A-plane ip; block loops jp = 0..(3-ip), one full
// K=4096 sweep per jp, writing C-slice CBASE[ip]+jp = A_ip @ B_jp^T.
// A-plane HBM-streamed once (j=0), L3-hit for j>=1; B-planes L2-resident.
// R9-verified body: BM=BN=128 (N pad 384), BK=128, 4 waves 2x2, wave 64x64,
// i8 MFMA 16x16x64, single 32KB buffer, 2 barriers/tile, gload16 + XOR
// chunk swizzle (8 chunks/row) -> 0 bank conflicts.
__global__ __launch_bounds__(256) void ozaki3_k(
    const signed char* __restrict__ Ap,   // [4][NN][NN]
    const signed char* __restrict__ Bp,   // [4][DIM][NN]
    int* __restrict__ Cg)                 // [10][NN][DIM]
{
  constexpr int BM = 128, BN = 128, BK = 128;
  __shared__ __align__(16) signed char As[BM * BK];
  __shared__ __align__(16) signed char Bs[BN * BK];
  const int tid  = threadIdx.x;
  const int wave = tid >> 6, lane = tid & 63;
  const int wm = wave >> 1, wn = wave & 1;
  const int m0 = blockIdx.y * BM, n0 = blockIdx.x * BN;
  const int ml = lane & 15, g = lane >> 4;
  const int ip = blockIdx.z;
  const int njp = 4 - ip;
  constexpr int CBASE[4] = {0, 4, 7, 9};
  const signed char* Aq = Ap + (size_t)ip * NN * NN;

  // Staging sources: 4 A-chunks + 4 B-chunk offsets per thread, source
  // pre-swizzled (LDS chunk (r,c) holds global chunk c^(r&7); dest linear).
  const signed char* aptr[4];
  size_t boff[4];
#pragma unroll
  for (int i = 0; i < 4; ++i) {
    int ch = i * 256 + wave * 64 + lane;       // 0..1023
    int r = ch >> 3, c = ch & 7;
    int cs = c ^ (r & 7);
    aptr[i] = Aq + (size_t)(m0 + r) * NN + cs * 16;
    int rb = n0 + r; if (rb >= DIM) rb = DIM - 1;   // pad rows clamp
    boff[i] = (size_t)rb * NN + cs * 16;
  }

  const int crow = g * 4;
  for (int jp = 0; jp < njp; ++jp) {
    const signed char* Bq = Bp + (size_t)jp * DIM * NN;
    int* C = Cg + (size_t)(CBASE[ip] + jp) * NN * DIM;

    int4v acc[4][4];
#pragma unroll
    for (int i = 0; i < 4; ++i)
#pragma unroll
      for (int j = 0; j < 4; ++j) acc[i][j] = (int4v)0;

    for (int k0 = 0; k0 < NN; k0 += BK) {
#pragma unroll
      for (int i = 0; i < 4; ++i) {
        gload16(aptr[i] + k0, &As[(i * 256 + wave * 64) * 16]);
        gload16(Bq + boff[i] + k0, &Bs[(i * 256 + wave * 64) * 16]);
      }
      __syncthreads();                         // vmcnt(0) drain + barrier
#pragma unroll
      for (int ks = 0; ks < BK; ks += 64) {
        int4v aF[4], bF[4];
#pragma unroll
        for (int mi = 0; mi < 4; ++mi) {
          int row = wm * 64 + mi * 16 + ml;
          int cc = ((ks >> 4) + g) ^ (row & 7);
          aF[mi] = *(const int4v*)&As[row * 128 + cc * 16];
        }
#pragma unroll
        for (int ni = 0; ni < 4; ++ni) {
          int row = wn * 64 + ni * 16 + ml;
          int cc = ((ks >> 4) + g) ^ (row & 7);
          bF[ni] = *(const int4v*)&Bs[row * 128 + cc * 16];
        }
#pragma unroll
        for (int mi = 0; mi < 4; ++mi)
#pragma unroll
          for (int ni = 0; ni < 4; ++ni)
            acc[mi][ni] = __builtin_amdgcn_mfma_i32_16x16x64_i8(
                aF[mi], bF[ni], acc[mi][ni], 0, 0, 0);
      }
      __syncthreads();                         // guards LDS reuse (next tile/jp)
    }

#pragma unroll
    for (int mi = 0; mi < 4; ++mi)
#pragma unroll
      for (int ni = 0; ni < 4; ++ni) {
        int n = n0 + wn * 64 + ni * 16 + ml;
        if (n >= DIM) continue;
#pragma unroll
        for (int r = 0; r < 4; ++r) {
          int m = m0 + wm * 64 + mi * 16 + crow + r;
          C[(size_t)m * DIM + n] = acc[mi][ni][r];
        }
      }
  }
}

// Reassemble: T = M*2^-13 * sum_s 2^-7s * (sum of pair-partials with i+j=s).
// Slice order (by ip): s-groups are {0},{1,4},{2,5,7},{3,6,8,9}.
__global__ __launch_bounds__(256) void reasm2_k(
    const int* __restrict__ P, const unsigned long long* __restrict__ Msc,
    double* __restrict__ T, int n)
{
  int gi = blockIdx.x * 256 + threadIdx.x;
  if (gi >= n) return;
  const size_t str = (size_t)NN * DIM;
  int v0 = P[gi];
  int v1 = P[1 * str + gi] + P[4 * str + gi];
  int v2 = P[2 * str + gi] + P[5 * str + gi] + P[7 * str + gi];
  int v3 = P[3 * str + gi] + P[6 * str + gi] + P[8 * str + gi] + P[9 * str + gi];
  double Mv = oz_scale(Msc);
  T[gi] = Mv * 0x1p-13 * ((double)v0 + 0x1p-7 * (double)v1 +
                          0x1p-14 * (double)v2 + 0x1p-21 * (double)v3);
}

// fixed-order f32 partial reduce -> bf16
__global__ __launch_bounds__(256) void reduceb_k(
    const float* __restrict__ P, __hip_bfloat16* __restrict__ dst,
    int n, int nparts, size_t stride)
{
  int g = (blockIdx.x * 256 + threadIdx.x) * 4;
  if (g >= n) return;
  float4 s = *(const float4*)(P + g);
  for (int p = 1; p < nparts; ++p) {
    float4 v = *(const float4*)(P + p * stride + g);
    s.x += v.x; s.y += v.y; s.z += v.z; s.w += v.w;
  }
  dst[g]     = __float2bfloat16(s.x);
  dst[g + 1] = __float2bfloat16(s.y);
  dst[g + 2] = __float2bfloat16(s.z);
  dst[g + 3] = __float2bfloat16(s.w);
}

// ---------------- bf16 big A-GEMM: C = A @ Bt^T, split-K partials ------------
// A: NN x NN bf16 row-major. Bt: Nn x NN bf16 row-major. C: f32 partial at
// Cg + z*NN*ldc. ozaki structure clone: BM=BN=128 (pad Nn up), BK=64,
// 4 waves 2x2, wave 64x64, bf16 MFMA 16x16x32, gload16 + XOR chunk swizzle.
// R11: single 32KB buffer, 2 barriers/tile (dbuf reverted).
__global__ __launch_bounds__(256) void mfma2_k(
    const __hip_bfloat16* __restrict__ Ag, const __hip_bfloat16* __restrict__ Btg,
    float* __restrict__ Cg, int Nn, int klen, int ldc)
{
  constexpr int BM = 128, BN = 128, BK = 64;
  __shared__ __align__(16) ushort As[BM * BK];
  __shared__ __align__(16) ushort Bs[BN * BK];
  const int tid  = threadIdx.x;
  const int wave = tid >> 6, lane = tid & 63;
  const int wm = wave >> 1, wn = wave & 1;
  const int m0 = blockIdx.y * BM, n0 = blockIdx.x * BN;
  const int ml = lane & 15, g = lane >> 4;
  const int kof = blockIdx.z * klen;
  float* C = Cg + (size_t)blockIdx.z * NN * ldc;

  // 8 x 16B chunks per 64-elem bf16 row; 1024 chunks/operand; 4 per thread.
  const ushort* aptr[4];
  const ushort* bptr[4];
#pragma unroll
  for (int i = 0; i < 4; ++i) {
    int ch = i * 256 + wave * 64 + lane;
    int r = ch >> 3, c = ch & 7;
    int cs = c ^ (r & 7);
    aptr[i] = (const ushort*)Ag + (size_t)(m0 + r) * NN + cs * 8;
    int rb = n0 + r; if (rb >= Nn) rb = Nn - 1;
    bptr[i] = (const ushort*)Btg + (size_t)rb * NN + cs * 8;
  }

  floatx4 acc[4][4];
#pragma unroll
  for (int i = 0; i < 4; ++i)
#pragma unroll
    for (int j = 0; j < 4; ++j) acc[i][j] = (floatx4)0.f;

  const int nt = klen / BK;
  for (int t = 0; t < nt; ++t) {
    const int k0 = kof + t * BK;
#pragma unroll
    for (int i = 0; i < 4; ++i) {
      gload16(aptr[i] + k0, &As[(i * 256 + wave * 64) * 8]);
      gload16(bptr[i] + k0, &Bs[(i * 256 + wave * 64) * 8]);
    }
    __syncthreads();
#pragma unroll
    for (int ks = 0; ks < BK; ks += 32) {
      short8_t aF[4], bF[4];
#pragma unroll
      for (int mi = 0; mi < 4; ++mi) {
        int row = wm * 64 + mi * 16 + ml;
        int cc = ((ks >> 3) + g) ^ (row & 7);
        aF[mi] = *(const short8_t*)&As[row * 64 + cc * 8];
      }
#pragma unroll
      for (int ni = 0; ni < 4; ++ni) {
        int row = wn * 64 + ni * 16 + ml;
        int cc = ((ks >> 3) + g) ^ (row & 7);
        bF[ni] = *(const short8_t*)&Bs[row * 64 + cc * 8];
      }
#pragma unroll
      for (int mi = 0; mi < 4; ++mi)
#pragma unroll
        for (int ni = 0; ni < 4; ++ni)
          acc[mi][ni] = __builtin_amdgcn_mfma_f32_16x16x32_bf16(
              aF[mi], bF[ni], acc[mi][ni], 0, 0, 0);
    }
    __syncthreads();
  }

  const int crow = g * 4;
#pragma unroll
  for (int mi = 0; mi < 4; ++mi)
#pragma unroll
    for (int ni = 0; ni < 4; ++ni) {
      int n = n0 + wn * 64 + ni * 16 + ml;
      if (n >= Nn) continue;
#pragma unroll
      for (int r = 0; r < 4; ++r) {
        int m = m0 + wm * 64 + mi * 16 + crow + r;
        C[(size_t)m * ldc + n] = acc[mi][ni][r];
      }
    }
}

// ---------------- bf16 MFMA GEMM (feature GEMMs + pool_out) ------------------
template<int EPI, bool AGATHER, bool OUTBF>
__global__ __launch_bounds__(256) void mfma_gemm_k(
    const __hip_bfloat16* __restrict__ Ag, const __hip_bfloat16* __restrict__ Btg,
    void* __restrict__ Cgv, const float* __restrict__ bias,
    const float* __restrict__ Rg, const int* __restrict__ aidx,
    int M, int N, int klen, int lda, int ldb, int ldc, int ldr)
{
  constexpr int BM = 128, BN = 64, BK = 64, BKP = 72;
  __shared__ ushort As[BM][BKP];
  __shared__ ushort Bs[BN][BKP];
  const int tid  = threadIdx.x;
  const int wave = tid >> 6, lane = tid & 63;
  const int wm = wave >> 1, wn = wave & 1;
  const int m0 = blockIdx.y * BM, n0 = blockIdx.x * BN;
  const int mlane = lane & 15;
  const int kq    = (lane >> 4) * 8;
  const int kof   = blockIdx.z * klen;
  const size_t zoff = (size_t)blockIdx.z * M * ldc;

  floatx4 acc[4][2];
#pragma unroll
  for (int i = 0; i < 4; ++i)
#pragma unroll
    for (int j = 0; j < 2; ++j) acc[i][j] = (floatx4)0.f;

  for (int k0 = kof; k0 < kof + klen; k0 += BK) {
#pragma unroll
    for (int i = 0; i < 4; ++i) {
      int ch = tid + i * 256;
      int r = ch >> 3, c8 = (ch & 7) * 8;
      int row = m0 + r; if (row >= M) row = M - 1;
      int ar = AGATHER ? aidx[row] : row;
      uint4 v = *(const uint4*)((const ushort*)Ag + (size_t)ar * lda + k0 + c8);
      *(uint4*)&As[r][c8] = v;
    }
#pragma unroll
    for (int i = 0; i < 2; ++i) {
      int ch = tid + i * 256;
      int r = ch >> 3, c8 = (ch & 7) * 8;
      int row = n0 + r; if (row >= N) row = N - 1;
      uint4 v = *(const uint4*)((const ushort*)Btg + (size_t)row * ldb + k0 + c8);
      *(uint4*)&Bs[r][c8] = v;
    }
    __syncthreads();
#pragma unroll
    for (int ks = 0; ks < BK; ks += 32) {
      short8_t aF[4], bF[2];
#pragma unroll
      for (int mi = 0; mi < 4; ++mi)
        aF[mi] = *(const short8_t*)&As[wm * 64 + mi * 16 + mlane][ks + kq];
#pragma unroll
      for (int ni = 0; ni < 2; ++ni)
        bF[ni] = *(const short8_t*)&Bs[wn * 32 + ni * 16 + mlane][ks + kq];
#pragma unroll
      for (int mi = 0; mi < 4; ++mi)
#pragma unroll
        for (int ni = 0; ni < 2; ++ni)
          acc[mi][ni] = __builtin_amdgcn_mfma_f32_16x16x32_bf16(
              aF[mi], bF[ni], acc[mi][ni], 0, 0, 0);
    }
    __syncthreads();
  }
  const int crow = (lane >> 4) * 4;
#pragma unroll
  for (int mi = 0; mi < 4; ++mi)
#pragma unroll
    for (int ni = 0; ni < 2; ++ni) {
      int n = n0 + wn * 32 + ni * 16 + mlane;
      if (n >= N) continue;
#pragma unroll
      for (int r = 0; r < 4; ++r) {
        int m = m0 + wm * 64 + mi * 16 + crow + r;
        if (m >= M) continue;
        float v = acc[mi][ni][r];
        if (EPI >= 1) { v += bias[n]; v = v > 0.f ? v : 0.f; }
        if (EPI == 2) v += Rg[(size_t)m * ldr + n];
        if (OUTBF) ((__hip_bfloat16*)Cgv)[zoff + (size_t)m * ldc + n] = __float2bfloat16(v);
        else       ((float*)Cgv)[zoff + (size_t)m * ldc + n] = v;
      }
    }
}

// ---------------- conversions ------------------------------------------------
__global__ __launch_bounds__(256) void cvtA_bf16_k(
    const float* __restrict__ src, __hip_bfloat16* __restrict__ dst, int n)
{
  int g = (blockIdx.x * 256 + threadIdx.x) * 4;
  if (g + 3 < n) {
    float4 v = *(const float4*)(src + g);
    dst[g]     = __float2bfloat16(v.x);
    dst[g + 1] = __float2bfloat16(v.y);
    dst[g + 2] = __float2bfloat16(v.z);
    dst[g + 3] = __float2bfloat16(v.w);
  } else {
    for (int i = g; i < n; ++i) dst[i] = __float2bfloat16(src[i]);
  }
}

__global__ __launch_bounds__(256) void cvt32to64_k(
    const float* __restrict__ src, double* __restrict__ dst, int n)
{
  int g = blockIdx.x * 256 + threadIdx.x;
  if (g < n) dst[g] = (double)src[g];
}

// f32 src[R][C] -> bf16 dst[C][R], 64x64 LDS tiles, conflict-free (+1 pad)
__global__ __launch_bounds__(256) void transpose_bf16_k(
    const float* __restrict__ src, __hip_bfloat16* __restrict__ dst, int R, int C)
{
  __shared__ float s[64][65];
  int r0 = blockIdx.y * 64, c0 = blockIdx.x * 64;
  int tid = threadIdx.x;
  int c = tid & 63, rr = tid >> 6;
  for (int i = 0; i < 64; i += 4) {
    int r = rr + i;
    s[r][c] = (r0 + r < R && c0 + c < C) ? src[(size_t)(r0 + r) * C + c0 + c] : 0.f;
  }
  __syncthreads();
  int r2 = tid & 63, cc = tid >> 6;
  for (int i = 0; i < 64; i += 4) {
    int c2 = cc + i;
    if (c0 + c2 < C && r0 + r2 < R)
      dst[(size_t)(c0 + c2) * R + r0 + r2] = __float2bfloat16(s[r2][c2]);
  }
}

// ---------------- pooling scores -> sort keys --------------------------------
__global__ __launch_bounds__(64) void score_keys_k(
    const double* __restrict__ Xd, const float* __restrict__ pw,
    const float* __restrict__ pb, int n, ulonglong2* __restrict__ keys)
{
  int i = blockIdx.x;
  int lane = threadIdx.x;
  if (i >= n) {
    if (lane == 0) { ulonglong2 kv; kv.x = 0ull; kv.y = 0xFFFFFFFFull; keys[i] = kv; }
    return;
  }
  double p = 0.0;
#pragma unroll
  for (int c = 0; c < DIM; c += 64)
    p += Xd[(size_t)i * DIM + c + lane] * (double)pw[c + lane];
  for (int o = 32; o > 0; o >>= 1) p += __shfl_down(p, o, 64);
  if (lane == 0) {
    double z = (p + (double)pb[0]) / 100.0;
    double s;
    if (z >= 0.0) s = 1.0 / (1.0 + exp(-z));
    else { double e = exp(z); s = e / (1.0 + e); }   // stable branch (jax/scipy)
    ulonglong2 kv;
    kv.x = (unsigned long long)__double_as_longlong(s);
    kv.y = (unsigned long long)i;
    keys[i] = kv;
  }
}

__device__ __forceinline__ bool key_gt(const ulonglong2 a, const ulonglong2 b) {
  return (a.x > b.x) || (a.x == b.x && a.y < b.y);
}

// Bitonic split (R9). Directions from GLOBAL element index: desc = ((tg&k)==0).
// (1) local: 2 blocks sort 2048-key chunks for k=2..2048 (all j in-chunk).
__global__ __launch_bounds__(1024) void bitonic_local_k(ulonglong2* __restrict__ keys)
{
  __shared__ ulonglong2 s[2048];
  const int tid = threadIdx.x;
  const int base = blockIdx.x * 2048;
  s[tid]        = keys[base + tid];
  s[tid + 1024] = keys[base + tid + 1024];
  __syncthreads();
  for (int k = 2; k <= 2048; k <<= 1) {
    for (int j = k >> 1; j > 0; j >>= 1) {
      for (int t = tid; t < 2048; t += 1024) {
        int p = t ^ j;
        if (p > t) {
          ulonglong2 a = s[t], b = s[p];
          bool desc = (((base + t) & k) == 0);
          bool sw = desc ? key_gt(b, a) : key_gt(a, b);
          if (sw) { s[t] = b; s[p] = a; }
        }
      }
      __syncthreads();
    }
  }
  keys[base + tid]        = s[tid];
  keys[base + tid + 1024] = s[tid + 1024];
}

// (2) global phase k=4096, j=2048: desc true for all t.
__global__ __launch_bounds__(256) void bitonic_gphase_k(ulonglong2* __restrict__ keys)
{
  int t = blockIdx.x * 256 + threadIdx.x;    // 2048 pairs
  if (t >= 2048) return;
  int p = t | 2048;
  ulonglong2 a = keys[t], b = keys[p];
  if (key_gt(b, a)) { keys[t] = b; keys[p] = a; }
}

// (3) final: k=4096, j=1024..1 (in-chunk), desc always true; emit top k_keep.
__global__ __launch_bounds__(1024) void bitonic_final_k(
    const ulonglong2* __restrict__ keys, int k_keep,
    int* __restrict__ idx, double* __restrict__ vals)
{
  __shared__ ulonglong2 s[2048];
  const int tid = threadIdx.x;
  const int base = blockIdx.x * 2048;
  s[tid]        = keys[base + tid];
  s[tid + 1024] = keys[base + tid + 1024];
  __syncthreads();
  for (int j = 1024; j > 0; j >>= 1) {
    for (int t = tid; t < 2048; t += 1024) {
      int p = t ^ j;
      if (p > t) {
        ulonglong2 a = s[t], b = s[p];
        if (key_gt(b, a)) { s[t] = b; s[p] = a; }
      }
    }
    __syncthreads();
  }
  for (int t = tid; t < 2048; t += 1024) {
    int r = base + t;
    if (r < k_keep) {
      idx[r]  = (int)s[t].y;
      vals[r] = __longlong_as_double((long long)s[t].x);
    }
  }
}

// ---------------- small helpers ----------------------------------------------
__global__ void scatter64_k(const double* __restrict__ src, const int* __restrict__ sel,
                            const double* __restrict__ vals, const int* __restrict__ scat,
                            double* __restrict__ dst, __hip_bfloat16* __restrict__ comp,
                            int kcnt)
{
  int g = blockIdx.x * 256 + threadIdx.x;
  if (g >= kcnt * DIM) return;
  int r = g / DIM, c = g % DIM;
  double v = src[(size_t)sel[r] * DIM + c] * vals[r];
  dst[(size_t)scat[r] * DIM + c] = v;
  comp[g] = __float2bfloat16((float)v);
}

__global__ void scatter32_from64_k(const double* __restrict__ src, const int* __restrict__ sel,
                                   const double* __restrict__ vals, const int* __restrict__ scat,
                                   float* __restrict__ dst, int kcnt)
{
  int g = blockIdx.x * 256 + threadIdx.x;
  if (g >= kcnt * DIM) return;
  int r = g / DIM, c = g % DIM;
  dst[(size_t)scat[r] * DIM + c] = (float)(src[(size_t)sel[r] * DIM + c] * vals[r]);
}

__global__ void scatter32_k(const float* __restrict__ src, const int* __restrict__ scat,
                            float* __restrict__ dst, int kcnt)
{
  int g = blockIdx.x * 256 + threadIdx.x;
  if (g >= kcnt * DIM) return;
  int r = g / DIM, c = g % DIM;
  dst[(size_t)scat[r] * DIM + c] = src[g];
}

__global__ void cvt64to32_k(const double* __restrict__ src, float* __restrict__ dst, int n)
{
  int g = blockIdx.x * 256 + threadIdx.x;
  if (g < n) dst[g] = (float)src[g];
}

__global__ void compose_k(const int* __restrict__ idx0, const int* __restrict__ idx1,
                          int* __restrict__ idx01, int n)
{
  int g = blockIdx.x * 256 + threadIdx.x;
  if (g < n) idx01[g] = idx0[idx1[g]];
}

__global__ void copycols_k(float* __restrict__ xcat, const float* __restrict__ x0)
{
  int g = blockIdx.x * 256 + threadIdx.x;
  if (g >= NN * DIM) return;
  int r = g / DIM, c = g % DIM;
  xcat[(size_t)r * (2 * DIM) + DIM + c] = x0[g];
}

__global__ void diag_k(float* __restrict__ po)
{
  int g = blockIdx.x * 256 + threadIdx.x;
  if (g < KP0) po[(size_t)g * KP0 + g] = 1.0f;
}

// ---------------- launch ------------------------------------------------------
extern "C" void kernel_launch(void* const* d_in, const int* in_sizes, int n_in,
                              void* d_out, int out_size, void* d_ws, size_t ws_size,
                              hipStream_t stream) {
  const float* A        = (const float*)d_in[0];
  const float* X        = (const float*)d_in[1];
  const float* w_start  = (const float*)d_in[2];
  const float* b_start  = (const float*)d_in[3];
  const float* w_down0  = (const float*)d_in[4];
  const float* b_down0  = (const float*)d_in[5];
  const float* w_down1  = (const float*)d_in[6];
  const float* b_down1  = (const float*)d_in[7];
  const float* p_w0     = (const float*)d_in[8];
  const float* p_b0     = (const float*)d_in[9];
  const float* p_w1     = (const float*)d_in[10];
  const float* p_b1     = (const float*)d_in[11];
  const float* w_bottom = (const float*)d_in[12];
  const float* b_bottom = (const float*)d_in[13];
  const float* w_up0    = (const float*)d_in[14];
  const float* b_up0    = (const float*)d_in[15];
  const float* w_up1    = (const float*)d_in[16];
  const float* b_up1    = (const float*)d_in[17];
  const float* w_end    = (const float*)d_in[18];
  const float* b_end    = (const float*)d_in[19];

  float* out_x  = (float*)d_out;             // Xout   [4096,320]
  float* out_x0 = out_x + NN * DIM;          // X0     [4096,320]
  float* out_po = out_x0 + NN * DIM;         // pool   [3686,3686]

  char*  wsb = (char*)d_ws;
  size_t off = 0;
  auto alloc = [&](size_t bytes) -> void* {
    void* p = wsb + off; off = (off + bytes + 255) & ~(size_t)255; return p;
  };
  double* B1   = (double*)alloc((size_t)NN * DIM * 8);
  double* B2   = (double*)alloc((size_t)NN * DIM * 8);
  double* B3   = (double*)alloc((size_t)NN * DIM * 8);
  double* Ws64 = (double*)alloc((size_t)DIM * DIM * 8);
  double* Wd064= (double*)alloc((size_t)DIM * DIM * 8);
  double* Wd164= (double*)alloc((size_t)DIM * DIM * 8);
  float*  Xd0f = (float*) alloc((size_t)NN * DIM * 4);
  float*  Xd1f = (float*) alloc((size_t)KP0 * DIM * 4);
  float*  Xs32 = (float*) alloc((size_t)NN * DIM * 4);
  float*  Xc   = (float*) alloc((size_t)KP0 * DIM * 4);
  float*  Xcat = (float*) alloc((size_t)NN * 2 * DIM * 4);
  // Shared scratch: i8 pair partials (10 x NN x DIM i32 = 52MB, down path)
  // overlaid with bf16 split-K f32 partials (4 x NN x 2DIM f32 = 42MB, up).
  char*   Scr  = (char*)  alloc((size_t)16 * NN * DIM * 4);
  int*    Iprt = (int*)   Scr;
  float*  Pf   = (float*) Scr;
  signed char* Apl = (signed char*)alloc((size_t)4 * NN * NN);
  signed char* Bpl = (signed char*)alloc((size_t)4 * DIM * NN);
  unsigned long long* Msc = (unsigned long long*)alloc(256);
  __hip_bfloat16* Abf  = (__hip_bfloat16*)alloc((size_t)NN * NN * 2);
  __hip_bfloat16* XbfT = (__hip_bfloat16*)alloc((size_t)2 * DIM * NN * 2);
  __hip_bfloat16* Tbf  = (__hip_bfloat16*)alloc((size_t)NN * 2 * DIM * 2);
  __hip_bfloat16* Pbf  = (__hip_bfloat16*)alloc((size_t)KP0 * DIM * 2);
  __hip_bfloat16* wbT  = (__hip_bfloat16*)alloc((size_t)DIM * DIM * 2);
  __hip_bfloat16* wu0T = (__hip_bfloat16*)alloc((size_t)DIM * DIM * 2);
  __hip_bfloat16* wu1T = (__hip_bfloat16*)alloc((size_t)DIM * DIM * 2);
  __hip_bfloat16* weT  = (__hip_bfloat16*)alloc((size_t)DIM * 2 * DIM * 2);
  ulonglong2* keys = (ulonglong2*)alloc((size_t)NN * 16);
  int*    idx0  = (int*)   alloc(4096 * 4);
  double* vals0 = (double*)alloc(4096 * 8);
  int*    idx1  = (int*)   alloc(4096 * 4);
  double* vals1 = (double*)alloc(4096 * 8);
  int*    idx01 = (int*)   alloc(4096 * 4);

  const dim3 blk(256);
  auto cdiv = [](int a, int b) { return (a + b - 1) / b; };
  const dim3 gd_sm  (DIM / 32, NN / 64, 1);          // f64 small-K GEMM
  const dim3 gd_smk0(DIM / 32, cdiv(KP0, 64), 1);
  const size_t strd64 = (size_t)NN * DIM;

  // Big GEMM via Ozaki-i8: maxabs -> slice -> 1 merged-pair dispatch -> reassemble
  auto big_gemm = [&](const void* Y, bool f64in, double* Tout) {
    hipMemsetAsync(Msc, 0, 8, stream);
    if (f64in) {
      maxabs_k<double><<<256, blk, 0, stream>>>((const double*)Y, Msc, NN * DIM);
      sliceYT_k<double><<<dim3(5, 64), blk, 0, stream>>>((const double*)Y, Msc, Bpl);
    } else {
      maxabs_k<float><<<256, blk, 0, stream>>>((const float*)Y, Msc, NN * DIM);
      sliceYT_k<float><<<dim3(5, 64), blk, 0, stream>>>((const float*)Y, Msc, Bpl);
    }
    ozaki3_k<<<dim3(3, 32, 4), blk, 0, stream>>>(Apl, Bpl, Iprt);
    reasm2_k<<<cdiv(NN * DIM, 256), blk, 0, stream>>>(Iprt, Msc, Tout, NN * DIM);
  };

  auto topk = [&](int k_keep, int* idx, double* vals) {
    bitonic_local_k<<<2, dim3(1024), 0, stream>>>(keys);
    bitonic_gphase_k<<<8, blk, 0, stream>>>(keys);
    bitonic_final_k<<<2, dim3(1024), 0, stream>>>(keys, k_keep, idx, vals);
  };

  // One-time conversions
  cvtA_bf16_k<<<cdiv(NN * NN / 4, 256), blk, 0, stream>>>(A, Abf, NN * NN);
  sliceA_k<<<cdiv(NN * NN / 4, 256), blk, 0, stream>>>(A, Apl);
  cvt32to64_k<<<cdiv(DIM * DIM, 256), blk, 0, stream>>>(w_start, Ws64,  DIM * DIM);
  cvt32to64_k<<<cdiv(DIM * DIM, 256), blk, 0, stream>>>(w_down0, Wd064, DIM * DIM);
  cvt32to64_k<<<cdiv(DIM * DIM, 256), blk, 0, stream>>>(w_down1, Wd164, DIM * DIM);
  transpose_bf16_k<<<dim3(5, 5),  blk, 0, stream>>>(w_bottom, wbT,  DIM, DIM);
  transpose_bf16_k<<<dim3(5, 5),  blk, 0, stream>>>(w_up0,    wu0T, DIM, DIM);
  transpose_bf16_k<<<dim3(5, 5),  blk, 0, stream>>>(w_up1,    wu1T, DIM, DIM);
  transpose_bf16_k<<<dim3(5, 10), blk, 0, stream>>>(w_end,    weT,  2 * DIM, DIM);

  // ---- down path: big A-GEMMs in exact-i8, feature GEMMs in f64 MFMA ----
  // 1) T = A @ X
  big_gemm(X, false, B1);
  // 2) X0 = relu(T @ w_start + b)
  dmfma_k<double, 1, false><<<gd_sm, blk, 0, stream>>>(
      B1, Ws64, B2, b_start, nullptr, NN, DIM, DIM, DIM, DIM, DIM);
  cvt64to32_k<<<cdiv(NN * DIM, 256), blk, 0, stream>>>(B2, out_x0, NN * DIM);
  // 3) T = A @ X0
  big_gemm(B2, true, B1);
  // 4) Xd0 = relu(T @ w_down0 + b)
  dmfma_k<double, 1, false><<<gd_sm, blk, 0, stream>>>(
      B1, Wd064, B3, b_down0, nullptr, NN, DIM, DIM, DIM, DIM, DIM);
  cvt64to32_k<<<cdiv(NN * DIM, 256), blk, 0, stream>>>(B3, Xd0f, NN * DIM);
  // 5) pool0 scores -> sort -> idx0, vals0
  score_keys_k<<<NN, dim3(64), 0, stream>>>(B3, p_w0, p_b0, NN, keys);
  topk(KP0, idx0, vals0);
  // 6) Xp0: scattered f64 + compact bf16 (for pool_out)
  hipMemsetAsync(B2, 0, (size_t)NN * DIM * 8, stream);
  scatter64_k<<<cdiv(KP0 * DIM, 256), blk, 0, stream>>>(B3, idx0, vals0, idx0, B2, Pbf, KP0);
  // 7) T = A @ Xp0s ; Xd1 = relu(gather_idx0(T) @ w_down1 + b)
  big_gemm(B2, true, B1);
  dmfma_k<double, 1, true><<<gd_smk0, blk, 0, stream>>>(
      B1, Wd164, B2, b_down1, idx0, KP0, DIM, DIM, DIM, DIM, DIM);
  cvt64to32_k<<<cdiv(KP0 * DIM, 256), blk, 0, stream>>>(B2, Xd1f, KP0 * DIM);
  // 8) pool1 scores -> idx1, vals1, idx01
  score_keys_k<<<NN, dim3(64), 0, stream>>>(B2, p_w1, p_b1, KP0, keys);
  topk(KP1, idx1, vals1);
  compose_k<<<cdiv(KP1, 256), blk, 0, stream>>>(idx0, idx1, idx01, KP1);

  // ---- up path, bf16 MFMA (big A-GEMMs: mfma2_k, split-K=4, klen=1024) ----
  // 9) Xb = relu(gather_idx01(A@Xp1s) @ w_bottom + b)
  hipMemsetAsync(Xs32, 0, (size_t)NN * DIM * 4, stream);
  scatter32_from64_k<<<cdiv(KP1 * DIM, 256), blk, 0, stream>>>(B2, idx1, vals1, idx01, Xs32, KP1);
  transpose_bf16_k<<<dim3(5, 64), blk, 0, stream>>>(Xs32, XbfT, NN, DIM);
  mfma2_k<<<dim3(3, 32, 4), blk, 0, stream>>>(Abf, XbfT, Pf, DIM, 1024, DIM);
  reduceb_k<<<cdiv(NN * DIM / 4, 256), blk, 0, stream>>>(Pf, Tbf, NN * DIM, 4, strd64);
  mfma_gemm_k<1, true, false><<<dim3(5, cdiv(KP1, 128), 1), blk, 0, stream>>>(
      Tbf, wbT, Xc, b_bottom, nullptr, idx01, KP1, DIM, DIM, DIM, DIM, DIM, 0);
  // 10) Xu = relu(gather_idx0(A@scatter_idx01(Xb)) @ w_up0 + b) + Xd1
  hipMemsetAsync(Xs32, 0, (size_t)NN * DIM * 4, stream);
  scatter32_k<<<cdiv(KP1 * DIM, 256), blk, 0, stream>>>(Xc, idx01, Xs32, KP1);
  transpose_bf16_k<<<dim3(5, 64), blk, 0, stream>>>(Xs32, XbfT, NN, DIM);
  mfma2_k<<<dim3(3, 32, 4), blk, 0, stream>>>(Abf, XbfT, Pf, DIM, 1024, DIM);
  reduceb_k<<<cdiv(NN * DIM / 4, 256), blk, 0, stream>>>(Pf, Tbf, NN * DIM, 4, strd64);
  mfma_gemm_k<2, true, false><<<dim3(5, cdiv(KP0, 128), 1), blk, 0, stream>>>(
      Tbf, wu0T, Xc, b_up0, Xd1f, idx0, KP0, DIM, DIM, DIM, DIM, DIM, DIM);
  // 11) Xu2 = relu(A@scatter_idx0(Xu) @ w_up1 + b) + Xd0  -> Xcat[:, :320]
  hipMemsetAsync(Xs32, 0, (size_t)NN * DIM * 4, stream);
  scatter32_k<<<cdiv(KP0 * DIM, 256), blk, 0, stream>>>(Xc, idx0, Xs32, KP0);
  transpose_bf16_k<<<dim3(5, 64), blk, 0, stream>>>(Xs32, XbfT, NN, DIM);
  mfma2_k<<<dim3(3, 32, 4), blk, 0, stream>>>(Abf, XbfT, Pf, DIM, 1024, DIM);
  reduceb_k<<<cdiv(NN * DIM / 4, 256), blk, 0, stream>>>(Pf, Tbf, NN * DIM, 4, strd64);
  mfma_gemm_k<2, false, false><<<dim3(5, 32, 1), blk, 0, stream>>>(
      Tbf, wu1T, Xcat, b_up1, Xd0f, nullptr, NN, DIM, DIM, DIM, DIM, 2 * DIM, DIM);
  copycols_k<<<cdiv(NN * DIM, 256), blk, 0, stream>>>(Xcat, out_x0);
  // 12) Xout = relu((A@Xcat) @ w_end + b_end)
  transpose_bf16_k<<<dim3(10, 64), blk, 0, stream>>>(Xcat, XbfT, NN, 2 * DIM);
  mfma2_k<<<dim3(5, 32, 4), blk, 0, stream>>>(Abf, XbfT, Pf, 2 * DIM, 1024, 2 * DIM);
  reduceb_k<<<cdiv(NN * 2 * DIM / 4, 256), blk, 0, stream>>>(
      Pf, Tbf, NN * 2 * DIM, 4, (size_t)NN * 2 * DIM);
  mfma_gemm_k<1, false, false><<<dim3(5, 32, 1), blk, 0, stream>>>(
      Tbf, weT, out_x, b_end, nullptr, nullptr, NN, DIM, 2 * DIM, 2 * DIM, 2 * DIM, DIM, 0);
  // 13) pool_out = Xp0 @ Xp0^T (both operands row-major-in-K), diag = 1
  mfma_gemm_k<0, false, false><<<dim3(cdiv(KP0, 64), cdiv(KP0, 128), 1), blk, 0, stream>>>(
      Pbf, Pbf, out_po, nullptr, nullptr, nullptr, KP0, KP0, DIM, DIM, DIM, KP0, 0);
  diag_k<<<cdiv(KP0, 256), blk, 0, stream>>>(out_po);
}

// Round 6
// 1051.539 us; speedup vs baseline: 1.1993x; 1.1993x over previous
//
#include <hip/hip_runtime.h>
#include <hip/hip_bf16.h>

// GraphUnet forward.
//  - Down path precision strategy (feeds both top-k pools):
//    Big A-GEMMs (M=N=4096,K=4096 x DIM) via Ozaki-style exact-int8 on the
//    i8 matrix core:
//      A in [0,1) -> 4 unsigned 7-bit planes (exact f32 bit-slices).
//      Y -> 4 signed 7-bit planes vs power-of-2 scale M (|y_j| <= 64).
//      i8 MFMA accumulates in i32 EXACTLY (max 4096*127*64 ~ 3.3e7 << 2^31).
//      R12: back to the R9-verified structure: ONE dispatch, gridDim.z = 10 =
//      one (i,j) plane-pair per z (i+j<=3), K=4096 each, 960 uniform blocks;
//      pairs in R10's ip-order (consecutive z share an A-plane through L3,
//      FETCH 196->160MB verified in R10). Reassembly groups slices by s=i+j:
//      {0},{1,4},{2,5,7},{3,6,8,9} -> bit-identical integer sums.
//      T = M*2^-13*sum_s 2^-7s C_s, rel err ~1e-8 (f64-grade ranking).
//    A/B history: R9 single-buffer = 93us; R10 2-phase dbuf REGRESSED (111us,
//    64KB LDS cut residency; latency hidden by TLP not pipelining); R11
//    jp-merged grid REGRESSED (160us, 384 imbalanced blocks under-occupied,
//    FETCH up). Single 32KB buffer + 960 uniform blocks wins.
//    Kernel body: BM=BN=128 (N pad 384), BK=128, 4 waves 2x2, wave 64x64,
//    i8 MFMA 16x16x64, gload16 + XOR chunk swizzle -> 0 bank conflicts.
//    Small K=320 feature GEMMs (+bias+relu) stay f64 MFMA (R7 DMA pipeline);
//    R12: f32 output fused into epilogue (removes 3 cvt64to32 passes).
//  - Up path big A-GEMMs (bf16): mfma2_k, ozaki structure clone, single-buffer.
//  - top_k = bitonic sort, 3-dispatch split (R9).
//  - A1 = A[idx][:,idx] never materialized: A1@Y = gather_idx(A @ scatter_idx(Y)).

constexpr int NN  = 4096;
constexpr int DIM = 320;
constexpr int KP0 = 3686;
constexpr int KP1 = 2580;

typedef __attribute__((ext_vector_type(8))) short short8_t;
typedef __attribute__((ext_vector_type(4))) float floatx4;
typedef __attribute__((ext_vector_type(4))) double double4v;
typedef __attribute__((ext_vector_type(4))) int int4v;

// 16B global->LDS DMA. LDS dest is wave-uniform base; HW adds lane*16.
__device__ __forceinline__ void gload16(const void* g, void* l) {
  __builtin_amdgcn_global_load_lds(
      (__attribute__((address_space(1))) void*)g,
      (__attribute__((address_space(3))) void*)l, 16, 0, 0);
}

// ---------------- f64 MFMA GEMM: C = A @ B (+bias, relu) ---------------------
// Small K=320 feature GEMMs. A: M x K f64 row-major (rows optionally
// gathered). B: K x N f64 row-major. C: M x N f64 (+ optional fused f32
// copy to dst32, same ldc). Tiles 64x32, BK=32; 4 waves (2x2), wave =
// 32m x 16n. 2-phase dbuf, gload16 + XOR swizzle (R7).
template<typename TA, int EPI, bool AGATHER>
__global__ __launch_bounds__(256) void dmfma_k(
    const TA* __restrict__ Ag, const double* __restrict__ Bg, double* __restrict__ Cg,
    const float* __restrict__ bias, const int* __restrict__ aidx,
    float* __restrict__ dst32,
    int M, int N, int klen, int lda, int ldb, int ldc)
{
  constexpr int BM = 64, BN = 32, BK = 32;
  constexpr bool AF32 = (sizeof(TA) == 4);
  constexpr int ACPR = AF32 ? 8 : 16;       // A 16B-chunks per LDS row
  constexpr int ACPT = (BM * ACPR) / 256;   // A chunks per thread
  __shared__ __align__(16) TA     As[2][BM * BK];
  __shared__ __align__(16) double Bs[2][BK * BN];
  const int tid  = threadIdx.x;
  const int wave = tid >> 6, lane = tid & 63;
  const int wm = wave >> 1, wn = wave & 1;
  const int m0 = blockIdx.y * BM, n0 = blockIdx.x * BN;
  const int ml = lane & 15, kl = lane >> 4;
  const int kof = blockIdx.z * klen;
  Cg += (size_t)blockIdx.z * M * ldc;

  const TA* aptr[ACPT];
#pragma unroll
  for (int i = 0; i < ACPT; ++i) {
    int ch = (wave * ACPT + i) * 64 + lane;
    int r = ch / ACPR, c = ch % ACPR;
    int row = m0 + r; if (row >= M) row = M - 1;
    int ar = AGATHER ? aidx[row] : row;
    int csrc = c ^ (r & (ACPR - 1));
    aptr[i] = Ag + (size_t)ar * lda + csrc * (16 / (int)sizeof(TA));
  }
  const double* bptr[2];
#pragma unroll
  for (int i = 0; i < 2; ++i) {
    int ch = (wave * 2 + i) * 64 + lane;
    int r = ch >> 4, c = ch & 15;
    int csrc = c ^ ((r & 3) << 2);
    bptr[i] = Bg + (size_t)r * ldb + n0 + csrc * 2;
  }

  auto stage = [&](int buf, int k0) {
#pragma unroll
    for (int i = 0; i < ACPT; ++i)
      gload16(aptr[i] + k0, &As[buf][(wave * ACPT + i) * (1024 / (int)sizeof(TA))]);
#pragma unroll
    for (int i = 0; i < 2; ++i)
      gload16(bptr[i] + (size_t)k0 * ldb, &Bs[buf][(wave * 2 + i) * 128]);
  };

  double4v acc[2];
#pragma unroll
  for (int i = 0; i < 2; ++i)
#pragma unroll
    for (int r = 0; r < 4; ++r) acc[i][r] = 0.0;

  const int nB = wn * 16 + ml;
  const int bconst = ((((nB >> 1) ^ (kl << 2)) << 1) | (nB & 1));
  const int mA = wm * 32 + ml;
  const int m7 = ml & 7;
  const int abase_f32 = mA * 32 + kl;
  const int abase_f64 = mA * 32 + (kl & 1);

  stage(0, kof);
  __syncthreads();
  int cur = 0;
  const int nt = klen / BK;
  for (int t = 0; t < nt; ++t) {
    if (t + 1 < nt) stage(cur ^ 1, kof + (t + 1) * BK);
    const TA*     Af = As[cur];
    const double* Bf = Bs[cur];
#pragma unroll
    for (int ks = 0; ks < BK; ks += 4) {
      double b = Bf[bconst + (ks + kl) * 32];
      double a0, a1;
      if constexpr (AF32) {
        int ia = abase_f32 + (((ks >> 2) ^ m7) << 2);
        a0 = (double)Af[ia];
        a1 = (double)Af[ia + 512];
      } else {
        int ia = abase_f64 + ((((ks + kl) >> 1) ^ ml) << 1);
        a0 = (double)Af[ia];
        a1 = (double)Af[ia + 512];
      }
      acc[0] = __builtin_amdgcn_mfma_f64_16x16x4f64(a0, b, acc[0], 0, 0, 0);
      acc[1] = __builtin_amdgcn_mfma_f64_16x16x4f64(a1, b, acc[1], 0, 0, 0);
    }
    __syncthreads();
    cur ^= 1;
  }

  const int n = n0 + wn * 16 + ml;
#pragma unroll
  for (int mi = 0; mi < 2; ++mi)
#pragma unroll
    for (int r = 0; r < 4; ++r) {
      int m = m0 + wm * 32 + mi * 16 + kl * 4 + r;
      if (m >= M || n >= N) continue;
      double v = acc[mi][r];
      if (EPI == 1) { v += (double)bias[n]; v = v > 0.0 ? v : 0.0; }
      Cg[(size_t)m * ldc + n] = v;
      if (dst32) dst32[(size_t)m * ldc + n] = (float)v;
    }
}

// ---------------- Ozaki int8 machinery --------------------------------------
// A slice planes: A = sum_i a_i * 2^-7(i+1) + eps, a_i in [0,127], eps < 2^-28.
__global__ __launch_bounds__(256) void sliceA_k(
    const float* __restrict__ A, signed char* __restrict__ P)
{
  const size_t nn = (size_t)NN * NN;
  size_t g = ((size_t)blockIdx.x * 256 + threadIdx.x) * 4;
  if (g >= nn) return;
  float4 v = *(const float4*)(A + g);
  float fv[4] = {v.x, v.y, v.z, v.w};
  signed char out[4][4];
#pragma unroll
  for (int e = 0; e < 4; ++e) {
    float t = fv[e];
#pragma unroll
    for (int i = 0; i < 4; ++i) {
      t *= 128.f;
      int a = (int)t;              // floor (t >= 0), exact bit-slice
      t -= (float)a;
      out[i][e] = (signed char)a;
    }
  }
#pragma unroll
  for (int i = 0; i < 4; ++i)
    *(char4*)(P + (size_t)i * nn + g) =
        make_char4(out[i][0], out[i][1], out[i][2], out[i][3]);
}

// max |x| over array -> atomicMax on f64 bit pattern (nonneg -> monotone in ull)
template<typename T>
__global__ __launch_bounds__(256) void maxabs_k(
    const T* __restrict__ x, unsigned long long* __restrict__ out, int n)
{
  double m = 0.0;
  for (int i = blockIdx.x * 256 + threadIdx.x; i < n; i += gridDim.x * 256)
    m = fmax(m, fabs((double)x[i]));
  for (int o = 32; o > 0; o >>= 1) m = fmax(m, __shfl_down(m, o, 64));
  if ((threadIdx.x & 63) == 0 && m > 0.0)
    atomicMax(out, (unsigned long long)__double_as_longlong(m));
}

__device__ __forceinline__ double oz_scale(const unsigned long long* Msc) {
  double mx = __longlong_as_double((long long)*Msc);
  if (!(mx > 0.0)) return 1.0;
  int e; frexp(mx, &e);
  return ldexp(1.0, e);             // power of 2 >= mx
}

// Y [NN][DIM] (f32 or f64) -> 4 signed 7-bit planes, TRANSPOSED: Bp[4][DIM][NN].
// y = M*(y0*2^-6 + y1*2^-13 + y2*2^-20 + y3*2^-27) + eps, |eps| <= M*2^-28.
template<typename TIN>
__global__ __launch_bounds__(256) void sliceYT_k(
    const TIN* __restrict__ Y, const unsigned long long* __restrict__ Msc,
    signed char* __restrict__ Bp)
{
  __shared__ double s[64][65];
  const int c0 = blockIdx.x * 64;    // feature col
  const int r0 = blockIdx.y * 64;    // node row
  const int tid = threadIdx.x;
  const int c = tid & 63, rr = tid >> 6;
#pragma unroll
  for (int i = 0; i < 64; i += 4)
    s[rr + i][c] = (double)Y[(size_t)(r0 + rr + i) * DIM + c0 + c];
  __syncthreads();
  const double inv = 1.0 / oz_scale(Msc);   // exact (power of 2)
  const int r2 = tid & 63, cc = tid >> 6;
  const size_t ps = (size_t)DIM * NN;
  for (int i = 0; i < 64; i += 4) {
    int c2 = cc + i;
    double q = s[r2][c2] * inv;               // |q| <= 1, exact
    int y0 = __double2int_rn(q * 64.0);  double r = q * 64.0  - y0;
    int y1 = __double2int_rn(r * 128.0);        r = r * 128.0 - y1;
    int y2 = __double2int_rn(r * 128.0);        r = r * 128.0 - y2;
    int y3 = __double2int_rn(r * 128.0);
    size_t o = (size_t)(c0 + c2) * NN + (r0 + r2);
    Bp[o]          = (signed char)y0;
    Bp[ps + o]     = (signed char)y1;
    Bp[2 * ps + o] = (signed char)y2;
    Bp[3 * ps + o] = (signed char)y3;
  }
}

// R12 i8 GEMM: one (i,j) plane-pair per blockIdx.z, K=4096, 960 uniform
// blocks. Pairs in ip-order: z : (ip,jp) =
// (0,0)(0,1)(0,2)(0,3)(1,0)(1,1)(1,2)(2,0)(2,1)(3,0).
// Partial C_z = A_i @ B_j^T at Cg + z*NN*DIM. BM=BN=128 (N pad 384), BK=128,
// 4 waves 2x2, wave 64x64, i8 MFMA 16x16x64, single 32KB buffer,
// 2 barriers/tile, gload16 + XOR chunk swizzle -> 0 bank conflicts.
__global__ __launch_bounds__(256) void ozaki2b_k(
    const signed char* __restrict__ Ap,   // [4][NN][NN]
    const signed char* __restrict__ Bp,   // [4][DIM][NN]
    int* __restrict__ Cg)                 // [10][NN][DIM]
{
  constexpr int BM = 128, BN = 128, BK = 128;
  __shared__ __align__(16) signed char As[BM * BK];
  __shared__ __align__(16) signed char Bs[BN * BK];
  const int tid  = threadIdx.x;
  const int wave = tid >> 6, lane = tid & 63;
  const int wm = wave >> 1, wn = wave & 1;
  const int m0 = blockIdx.y * BM, n0 = blockIdx.x * BN;
  const int ml = lane & 15, g = lane >> 4;
  const int z = blockIdx.z;
  constexpr int IPT[10] = {0,0,0,0,1,1,1,2,2,3};
  constexpr int JPT[10] = {0,1,2,3,0,1,2,0,1,0};
  const int ip = IPT[z], jp = JPT[z];
  const signed char* Aq = Ap + (size_t)ip * NN * NN;
  const signed char* Bq = Bp + (size_t)jp * DIM * NN;
  int* C = Cg + (size_t)z * NN * DIM;

  // Staging sources: 4 A-chunks + 4 B-chunks per thread, source pre-swizzled
  // (LDS chunk (r,c) holds global chunk c^(r&7); gload16 dest is linear).
  const signed char* aptr[4];
  const signed char* bptr[4];
#pragma unroll
  for (int i = 0; i < 4; ++i) {
    int ch = i * 256 + wave * 64 + lane;       // 0..1023
    int r = ch >> 3, c = ch & 7;
    int cs = c ^ (r & 7);
    aptr[i] = Aq + (size_t)(m0 + r) * NN + cs * 16;
    int rb = n0 + r; if (rb >= DIM) rb = DIM - 1;   // pad rows clamp
    bptr[i] = Bq + (size_t)rb * NN + cs * 16;
  }

  int4v acc[4][4];
#pragma unroll
  for (int i = 0; i < 4; ++i)
#pragma unroll
    for (int j = 0; j < 4; ++j) acc[i][j] = (int4v)0;

  for (int k0 = 0; k0 < NN; k0 += BK) {
#pragma unroll
    for (int i = 0; i < 4; ++i) {
      gload16(aptr[i] + k0, &As[(i * 256 + wave * 64) * 16]);
      gload16(bptr[i] + k0, &Bs[(i * 256 + wave * 64) * 16]);
    }
    __syncthreads();                           // vmcnt(0) drain + barrier
#pragma unroll
    for (int ks = 0; ks < BK; ks += 64) {
      int4v aF[4], bF[4];
#pragma unroll
      for (int mi = 0; mi < 4; ++mi) {
        int row = wm * 64 + mi * 16 + ml;
        int cc = ((ks >> 4) + g) ^ (row & 7);
        aF[mi] = *(const int4v*)&As[row * 128 + cc * 16];
      }
#pragma unroll
      for (int ni = 0; ni < 4; ++ni) {
        int row = wn * 64 + ni * 16 + ml;
        int cc = ((ks >> 4) + g) ^ (row & 7);
        bF[ni] = *(const int4v*)&Bs[row * 128 + cc * 16];
      }
#pragma unroll
      for (int mi = 0; mi < 4; ++mi)
#pragma unroll
        for (int ni = 0; ni < 4; ++ni)
          acc[mi][ni] = __builtin_amdgcn_mfma_i32_16x16x64_i8(
              aF[mi], bF[ni], acc[mi][ni], 0, 0, 0);
    }
    __syncthreads();                           // guards LDS reuse
  }

  const int crow = g * 4;
#pragma unroll
  for (int mi = 0; mi < 4; ++mi)
#pragma unroll
    for (int ni = 0; ni < 4; ++ni) {
      int n = n0 + wn * 64 + ni * 16 + ml;
      if (n >= DIM) continue;
#pragma unroll
      for (int r = 0; r < 4; ++r) {
        int m = m0 + wm * 64 + mi * 16 + crow + r;
        C[(size_t)m * DIM + n] = acc[mi][ni][r];
      }
    }
}

// Reassemble: T = M*2^-13 * sum_s 2^-7s * (sum of pair-partials with i+j=s).
// Slice order (by ip): s-groups are {0},{1,4},{2,5,7},{3,6,8,9}.
__global__ __launch_bounds__(256) void reasm2_k(
    const int* __restrict__ P, const unsigned long long* __restrict__ Msc,
    double* __restrict__ T, int n)
{
  int gi = blockIdx.x * 256 + threadIdx.x;
  if (gi >= n) return;
  const size_t str = (size_t)NN * DIM;
  int v0 = P[gi];
  int v1 = P[1 * str + gi] + P[4 * str + gi];
  int v2 = P[2 * str + gi] + P[5 * str + gi] + P[7 * str + gi];
  int v3 = P[3 * str + gi] + P[6 * str + gi] + P[8 * str + gi] + P[9 * str + gi];
  double Mv = oz_scale(Msc);
  T[gi] = Mv * 0x1p-13 * ((double)v0 + 0x1p-7 * (double)v1 +
                          0x1p-14 * (double)v2 + 0x1p-21 * (double)v3);
}

// fixed-order f32 partial reduce -> bf16
__global__ __launch_bounds__(256) void reduceb_k(
    const float* __restrict__ P, __hip_bfloat16* __restrict__ dst,
    int n, int nparts, size_t stride)
{
  int g = (blockIdx.x * 256 + threadIdx.x) * 4;
  if (g >= n) return;
  float4 s = *(const float4*)(P + g);
  for (int p = 1; p < nparts; ++p) {
    float4 v = *(const float4*)(P + p * stride + g);
    s.x += v.x; s.y += v.y; s.z += v.z; s.w += v.w;
  }
  dst[g]     = __float2bfloat16(s.x);
  dst[g + 1] = __float2bfloat16(s.y);
  dst[g + 2] = __float2bfloat16(s.z);
  dst[g + 3] = __float2bfloat16(s.w);
}

// ---------------- bf16 big A-GEMM: C = A @ Bt^T, split-K partials ------------
// A: NN x NN bf16 row-major. Bt: Nn x NN bf16 row-major. C: f32 partial at
// Cg + z*NN*ldc. ozaki structure clone: BM=BN=128 (pad Nn up), BK=64,
// 4 waves 2x2, wave 64x64, bf16 MFMA 16x16x32, gload16 + XOR chunk swizzle,
// single 32KB buffer, 2 barriers/tile.
__global__ __launch_bounds__(256) void mfma2_k(
    const __hip_bfloat16* __restrict__ Ag, const __hip_bfloat16* __restrict__ Btg,
    float* __restrict__ Cg, int Nn, int klen, int ldc)
{
  constexpr int BM = 128, BN = 128, BK = 64;
  __shared__ __align__(16) ushort As[BM * BK];
  __shared__ __align__(16) ushort Bs[BN * BK];
  const int tid  = threadIdx.x;
  const int wave = tid >> 6, lane = tid & 63;
  const int wm = wave >> 1, wn = wave & 1;
  const int m0 = blockIdx.y * BM, n0 = blockIdx.x * BN;
  const int ml = lane & 15, g = lane >> 4;
  const int kof = blockIdx.z * klen;
  float* C = Cg + (size_t)blockIdx.z * NN * ldc;

  // 8 x 16B chunks per 64-elem bf16 row; 1024 chunks/operand; 4 per thread.
  const ushort* aptr[4];
  const ushort* bptr[4];
#pragma unroll
  for (int i = 0; i < 4; ++i) {
    int ch = i * 256 + wave * 64 + lane;
    int r = ch >> 3, c = ch & 7;
    int cs = c ^ (r & 7);
    aptr[i] = (const ushort*)Ag + (size_t)(m0 + r) * NN + cs * 8;
    int rb = n0 + r; if (rb >= Nn) rb = Nn - 1;
    bptr[i] = (const ushort*)Btg + (size_t)rb * NN + cs * 8;
  }

  floatx4 acc[4][4];
#pragma unroll
  for (int i = 0; i < 4; ++i)
#pragma unroll
    for (int j = 0; j < 4; ++j) acc[i][j] = (floatx4)0.f;

  const int nt = klen / BK;
  for (int t = 0; t < nt; ++t) {
    const int k0 = kof + t * BK;
#pragma unroll
    for (int i = 0; i < 4; ++i) {
      gload16(aptr[i] + k0, &As[(i * 256 + wave * 64) * 8]);
      gload16(bptr[i] + k0, &Bs[(i * 256 + wave * 64) * 8]);
    }
    __syncthreads();
#pragma unroll
    for (int ks = 0; ks < BK; ks += 32) {
      short8_t aF[4], bF[4];
#pragma unroll
      for (int mi = 0; mi < 4; ++mi) {
        int row = wm * 64 + mi * 16 + ml;
        int cc = ((ks >> 3) + g) ^ (row & 7);
        aF[mi] = *(const short8_t*)&As[row * 64 + cc * 8];
      }
#pragma unroll
      for (int ni = 0; ni < 4; ++ni) {
        int row = wn * 64 + ni * 16 + ml;
        int cc = ((ks >> 3) + g) ^ (row & 7);
        bF[ni] = *(const short8_t*)&Bs[row * 64 + cc * 8];
      }
#pragma unroll
      for (int mi = 0; mi < 4; ++mi)
#pragma unroll
        for (int ni = 0; ni < 4; ++ni)
          acc[mi][ni] = __builtin_amdgcn_mfma_f32_16x16x32_bf16(
              aF[mi], bF[ni], acc[mi][ni], 0, 0, 0);
    }
    __syncthreads();
  }

  const int crow = g * 4;
#pragma unroll
  for (int mi = 0; mi < 4; ++mi)
#pragma unroll
    for (int ni = 0; ni < 4; ++ni) {
      int n = n0 + wn * 64 + ni * 16 + ml;
      if (n >= Nn) continue;
#pragma unroll
      for (int r = 0; r < 4; ++r) {
        int m = m0 + wm * 64 + mi * 16 + crow + r;
        C[(size_t)m * ldc + n] = acc[mi][ni][r];
      }
    }
}

// ---------------- bf16 MFMA GEMM (feature GEMMs + pool_out) ------------------
template<int EPI, bool AGATHER, bool OUTBF>
__global__ __launch_bounds__(256) void mfma_gemm_k(
    const __hip_bfloat16* __restrict__ Ag, const __hip_bfloat16* __restrict__ Btg,
    void* __restrict__ Cgv, const float* __restrict__ bias,
    const float* __restrict__ Rg, const int* __restrict__ aidx,
    int M, int N, int klen, int lda, int ldb, int ldc, int ldr)
{
  constexpr int BM = 128, BN = 64, BK = 64, BKP = 72;
  __shared__ ushort As[BM][BKP];
  __shared__ ushort Bs[BN][BKP];
  const int tid  = threadIdx.x;
  const int wave = tid >> 6, lane = tid & 63;
  const int wm = wave >> 1, wn = wave & 1;
  const int m0 = blockIdx.y * BM, n0 = blockIdx.x * BN;
  const int mlane = lane & 15;
  const int kq    = (lane >> 4) * 8;
  const int kof   = blockIdx.z * klen;
  const size_t zoff = (size_t)blockIdx.z * M * ldc;

  floatx4 acc[4][2];
#pragma unroll
  for (int i = 0; i < 4; ++i)
#pragma unroll
    for (int j = 0; j < 2; ++j) acc[i][j] = (floatx4)0.f;

  for (int k0 = kof; k0 < kof + klen; k0 += BK) {
#pragma unroll
    for (int i = 0; i < 4; ++i) {
      int ch = tid + i * 256;
      int r = ch >> 3, c8 = (ch & 7) * 8;
      int row = m0 + r; if (row >= M) row = M - 1;
      int ar = AGATHER ? aidx[row] : row;
      uint4 v = *(const uint4*)((const ushort*)Ag + (size_t)ar * lda + k0 + c8);
      *(uint4*)&As[r][c8] = v;
    }
#pragma unroll
    for (int i = 0; i < 2; ++i) {
      int ch = tid + i * 256;
      int r = ch >> 3, c8 = (ch & 7) * 8;
      int row = n0 + r; if (row >= N) row = N - 1;
      uint4 v = *(const uint4*)((const ushort*)Btg + (size_t)row * ldb + k0 + c8);
      *(uint4*)&Bs[r][c8] = v;
    }
    __syncthreads();
#pragma unroll
    for (int ks = 0; ks < BK; ks += 32) {
      short8_t aF[4], bF[2];
#pragma unroll
      for (int mi = 0; mi < 4; ++mi)
        aF[mi] = *(const short8_t*)&As[wm * 64 + mi * 16 + mlane][ks + kq];
#pragma unroll
      for (int ni = 0; ni < 2; ++ni)
        bF[ni] = *(const short8_t*)&Bs[wn * 32 + ni * 16 + mlane][ks + kq];
#pragma unroll
      for (int mi = 0; mi < 4; ++mi)
#pragma unroll
        for (int ni = 0; ni < 2; ++ni)
          acc[mi][ni] = __builtin_amdgcn_mfma_f32_16x16x32_bf16(
              aF[mi], bF[ni], acc[mi][ni], 0, 0, 0);
    }
    __syncthreads();
  }
  const int crow = (lane >> 4) * 4;
#pragma unroll
  for (int mi = 0; mi < 4; ++mi)
#pragma unroll
    for (int ni = 0; ni < 2; ++ni) {
      int n = n0 + wn * 32 + ni * 16 + mlane;
      if (n >= N) continue;
#pragma unroll
      for (int r = 0; r < 4; ++r) {
        int m = m0 + wm * 64 + mi * 16 + crow + r;
        if (m >= M) continue;
        float v = acc[mi][ni][r];
        if (EPI >= 1) { v += bias[n]; v = v > 0.f ? v : 0.f; }
        if (EPI == 2) v += Rg[(size_t)m * ldr + n];
        if (OUTBF) ((__hip_bfloat16*)Cgv)[zoff + (size_t)m * ldc + n] = __float2bfloat16(v);
        else       ((float*)Cgv)[zoff + (size_t)m * ldc + n] = v;
      }
    }
}

// ---------------- conversions ------------------------------------------------
__global__ __launch_bounds__(256) void cvtA_bf16_k(
    const float* __restrict__ src, __hip_bfloat16* __restrict__ dst, int n)
{
  int g = (blockIdx.x * 256 + threadIdx.x) * 4;
  if (g + 3 < n) {
    float4 v = *(const float4*)(src + g);
    dst[g]     = __float2bfloat16(v.x);
    dst[g + 1] = __float2bfloat16(v.y);
    dst[g + 2] = __float2bfloat16(v.z);
    dst[g + 3] = __float2bfloat16(v.w);
  } else {
    for (int i = g; i < n; ++i) dst[i] = __float2bfloat16(src[i]);
  }
}

__global__ __launch_bounds__(256) void cvt32to64_k(
    const float* __restrict__ src, double* __restrict__ dst, int n)
{
  int g = blockIdx.x * 256 + threadIdx.x;
  if (g < n) dst[g] = (double)src[g];
}

// f32 src[R][C] -> bf16 dst[C][R], 64x64 LDS tiles, conflict-free (+1 pad)
__global__ __launch_bounds__(256) void transpose_bf16_k(
    const float* __restrict__ src, __hip_bfloat16* __restrict__ dst, int R, int C)
{
  __shared__ float s[64][65];
  int r0 = blockIdx.y * 64, c0 = blockIdx.x * 64;
  int tid = threadIdx.x;
  int c = tid & 63, rr = tid >> 6;
  for (int i = 0; i < 64; i += 4) {
    int r = rr + i;
    s[r][c] = (r0 + r < R && c0 + c < C) ? src[(size_t)(r0 + r) * C + c0 + c] : 0.f;
  }
  __syncthreads();
  int r2 = tid & 63, cc = tid >> 6;
  for (int i = 0; i < 64; i += 4) {
    int c2 = cc + i;
    if (c0 + c2 < C && r0 + r2 < R)
      dst[(size_t)(c0 + c2) * R + r0 + r2] = __float2bfloat16(s[r2][c2]);
  }
}

// ---------------- pooling scores -> sort keys --------------------------------
__global__ __launch_bounds__(64) void score_keys_k(
    const double* __restrict__ Xd, const float* __restrict__ pw,
    const float* __restrict__ pb, int n, ulonglong2* __restrict__ keys)
{
  int i = blockIdx.x;
  int lane = threadIdx.x;
  if (i >= n) {
    if (lane == 0) { ulonglong2 kv; kv.x = 0ull; kv.y = 0xFFFFFFFFull; keys[i] = kv; }
    return;
  }
  double p = 0.0;
#pragma unroll
  for (int c = 0; c < DIM; c += 64)
    p += Xd[(size_t)i * DIM + c + lane] * (double)pw[c + lane];
  for (int o = 32; o > 0; o >>= 1) p += __shfl_down(p, o, 64);
  if (lane == 0) {
    double z = (p + (double)pb[0]) / 100.0;
    double s;
    if (z >= 0.0) s = 1.0 / (1.0 + exp(-z));
    else { double e = exp(z); s = e / (1.0 + e); }   // stable branch (jax/scipy)
    ulonglong2 kv;
    kv.x = (unsigned long long)__double_as_longlong(s);
    kv.y = (unsigned long long)i;
    keys[i] = kv;
  }
}

__device__ __forceinline__ bool key_gt(const ulonglong2 a, const ulonglong2 b) {
  return (a.x > b.x) || (a.x == b.x && a.y < b.y);
}

// Bitonic split (R9). Directions from GLOBAL element index: desc = ((tg&k)==0).
// (1) local: 2 blocks sort 2048-key chunks for k=2..2048 (all j in-chunk).
__global__ __launch_bounds__(1024) void bitonic_local_k(ulonglong2* __restrict__ keys)
{
  __shared__ ulonglong2 s[2048];
  const int tid = threadIdx.x;
  const int base = blockIdx.x * 2048;
  s[tid]        = keys[base + tid];
  s[tid + 1024] = keys[base + tid + 1024];
  __syncthreads();
  for (int k = 2; k <= 2048; k <<= 1) {
    for (int j = k >> 1; j > 0; j >>= 1) {
      for (int t = tid; t < 2048; t += 1024) {
        int p = t ^ j;
        if (p > t) {
          ulonglong2 a = s[t], b = s[p];
          bool desc = (((base + t) & k) == 0);
          bool sw = desc ? key_gt(b, a) : key_gt(a, b);
          if (sw) { s[t] = b; s[p] = a; }
        }
      }
      __syncthreads();
    }
  }
  keys[base + tid]        = s[tid];
  keys[base + tid + 1024] = s[tid + 1024];
}

// (2) global phase k=4096, j=2048: desc true for all t.
__global__ __launch_bounds__(256) void bitonic_gphase_k(ulonglong2* __restrict__ keys)
{
  int t = blockIdx.x * 256 + threadIdx.x;    // 2048 pairs
  if (t >= 2048) return;
  int p = t | 2048;
  ulonglong2 a = keys[t], b = keys[p];
  if (key_gt(b, a)) { keys[t] = b; keys[p] = a; }
}

// (3) final: k=4096, j=1024..1 (in-chunk), desc always true; emit top k_keep.
__global__ __launch_bounds__(1024) void bitonic_final_k(
    const ulonglong2* __restrict__ keys, int k_keep,
    int* __restrict__ idx, double* __restrict__ vals)
{
  __shared__ ulonglong2 s[2048];
  const int tid = threadIdx.x;
  const int base = blockIdx.x * 2048;
  s[tid]        = keys[base + tid];
  s[tid + 1024] = keys[base + tid + 1024];
  __syncthreads();
  for (int j = 1024; j > 0; j >>= 1) {
    for (int t = tid; t < 2048; t += 1024) {
      int p = t ^ j;
      if (p > t) {
        ulonglong2 a = s[t], b = s[p];
        if (key_gt(b, a)) { s[t] = b; s[p] = a; }
      }
    }
    __syncthreads();
  }
  for (int t = tid; t < 2048; t += 1024) {
    int r = base + t;
    if (r < k_keep) {
      idx[r]  = (int)s[t].y;
      vals[r] = __longlong_as_double((long long)s[t].x);
    }
  }
}

// ---------------- small helpers ----------------------------------------------
__global__ void scatter64_k(const double* __restrict__ src, const int* __restrict__ sel,
                            const double* __restrict__ vals, const int* __restrict__ scat,
                            double* __restrict__ dst, __hip_bfloat16* __restrict__ comp,
                            int kcnt)
{
  int g = blockIdx.x * 256 + threadIdx.x;
  if (g >= kcnt * DIM) return;
  int r = g / DIM, c = g % DIM;
  double v = src[(size_t)sel[r] * DIM + c] * vals[r];
  dst[(size_t)scat[r] * DIM + c] = v;
  comp[g] = __float2bfloat16((float)v);
}

__global__ void scatter32_from64_k(const double* __restrict__ src, const int* __restrict__ sel,
                                   const double* __restrict__ vals, const int* __restrict__ scat,
                                   float* __restrict__ dst, int kcnt)
{
  int g = blockIdx.x * 256 + threadIdx.x;
  if (g >= kcnt * DIM) return;
  int r = g / DIM, c = g % DIM;
  dst[(size_t)scat[r] * DIM + c] = (float)(src[(size_t)sel[r] * DIM + c] * vals[r]);
}

__global__ void scatter32_k(const float* __restrict__ src, const int* __restrict__ scat,
                            float* __restrict__ dst, int kcnt)
{
  int g = blockIdx.x * 256 + threadIdx.x;
  if (g >= kcnt * DIM) return;
  int r = g / DIM, c = g % DIM;
  dst[(size_t)scat[r] * DIM + c] = src[g];
}

__global__ void compose_k(const int* __restrict__ idx0, const int* __restrict__ idx1,
                          int* __restrict__ idx01, int n)
{
  int g = blockIdx.x * 256 + threadIdx.x;
  if (g < n) idx01[g] = idx0[idx1[g]];
}

__global__ void copycols_k(float* __restrict__ xcat, const float* __restrict__ x0)
{
  int g = blockIdx.x * 256 + threadIdx.x;
  if (g >= NN * DIM) return;
  int r = g / DIM, c = g % DIM;
  xcat[(size_t)r * (2 * DIM) + DIM + c] = x0[g];
}

__global__ void diag_k(float* __restrict__ po)
{
  int g = blockIdx.x * 256 + threadIdx.x;
  if (g < KP0) po[(size_t)g * KP0 + g] = 1.0f;
}

// ---------------- launch ------------------------------------------------------
extern "C" void kernel_launch(void* const* d_in, const int* in_sizes, int n_in,
                              void* d_out, int out_size, void* d_ws, size_t ws_size,
                              hipStream_t stream) {
  const float* A        = (const float*)d_in[0];
  const float* X        = (const float*)d_in[1];
  const float* w_start  = (const float*)d_in[2];
  const float* b_start  = (const float*)d_in[3];
  const float* w_down0  = (const float*)d_in[4];
  const float* b_down0  = (const float*)d_in[5];
  const float* w_down1  = (const float*)d_in[6];
  const float* b_down1  = (const float*)d_in[7];
  const float* p_w0     = (const float*)d_in[8];
  const float* p_b0     = (const float*)d_in[9];
  const float* p_w1     = (const float*)d_in[10];
  const float* p_b1     = (const float*)d_in[11];
  const float* w_bottom = (const float*)d_in[12];
  const float* b_bottom = (const float*)d_in[13];
  const float* w_up0    = (const float*)d_in[14];
  const float* b_up0    = (const float*)d_in[15];
  const float* w_up1    = (const float*)d_in[16];
  const float* b_up1    = (const float*)d_in[17];
  const float* w_end    = (const float*)d_in[18];
  const float* b_end    = (const float*)d_in[19];

  float* out_x  = (float*)d_out;             // Xout   [4096,320]
  float* out_x0 = out_x + NN * DIM;          // X0     [4096,320]
  float* out_po = out_x0 + NN * DIM;         // pool   [3686,3686]

  char*  wsb = (char*)d_ws;
  size_t off = 0;
  auto alloc = [&](size_t bytes) -> void* {
    void* p = wsb + off; off = (off + bytes + 255) & ~(size_t)255; return p;
  };
  double* B1   = (double*)alloc((size_t)NN * DIM * 8);
  double* B2   = (double*)alloc((size_t)NN * DIM * 8);
  double* B3   = (double*)alloc((size_t)NN * DIM * 8);
  double* Ws64 = (double*)alloc((size_t)DIM * DIM * 8);
  double* Wd064= (double*)alloc((size_t)DIM * DIM * 8);
  double* Wd164= (double*)alloc((size_t)DIM * DIM * 8);
  float*  Xd0f = (float*) alloc((size_t)NN * DIM * 4);
  float*  Xd1f = (float*) alloc((size_t)KP0 * DIM * 4);
  float*  Xs32 = (float*) alloc((size_t)NN * DIM * 4);
  float*  Xc   = (float*) alloc((size_t)KP0 * DIM * 4);
  float*  Xcat = (float*) alloc((size_t)NN * 2 * DIM * 4);
  // Shared scratch: i8 pair partials (10 x NN x DIM i32 = 52MB, down path)
  // overlaid with bf16 split-K f32 partials (4 x NN x 2DIM f32 = 42MB, up).
  char*   Scr  = (char*)  alloc((size_t)16 * NN * DIM * 4);
  int*    Iprt = (int*)   Scr;
  float*  Pf   = (float*) Scr;
  signed char* Apl = (signed char*)alloc((size_t)4 * NN * NN);
  signed char* Bpl = (signed char*)alloc((size_t)4 * DIM * NN);
  unsigned long long* Msc = (unsigned long long*)alloc(256);
  __hip_bfloat16* Abf  = (__hip_bfloat16*)alloc((size_t)NN * NN * 2);
  __hip_bfloat16* XbfT = (__hip_bfloat16*)alloc((size_t)2 * DIM * NN * 2);
  __hip_bfloat16* Tbf  = (__hip_bfloat16*)alloc((size_t)NN * 2 * DIM * 2);
  __hip_bfloat16* Pbf  = (__hip_bfloat16*)alloc((size_t)KP0 * DIM * 2);
  __hip_bfloat16* wbT  = (__hip_bfloat16*)alloc((size_t)DIM * DIM * 2);
  __hip_bfloat16* wu0T = (__hip_bfloat16*)alloc((size_t)DIM * DIM * 2);
  __hip_bfloat16* wu1T = (__hip_bfloat16*)alloc((size_t)DIM * DIM * 2);
  __hip_bfloat16* weT  = (__hip_bfloat16*)alloc((size_t)DIM * 2 * DIM * 2);
  ulonglong2* keys = (ulonglong2*)alloc((size_t)NN * 16);
  int*    idx0  = (int*)   alloc(4096 * 4);
  double* vals0 = (double*)alloc(4096 * 8);
  int*    idx1  = (int*)   alloc(4096 * 4);
  double* vals1 = (double*)alloc(4096 * 8);
  int*    idx01 = (int*)   alloc(4096 * 4);

  const dim3 blk(256);
  auto cdiv = [](int a, int b) { return (a + b - 1) / b; };
  const dim3 gd_sm  (DIM / 32, NN / 64, 1);          // f64 small-K GEMM
  const dim3 gd_smk0(DIM / 32, cdiv(KP0, 64), 1);
  const size_t strd64 = (size_t)NN * DIM;

  // Big GEMM via Ozaki-i8: maxabs -> slice -> 1 pair-dispatch -> reassemble
  auto big_gemm = [&](const void* Y, bool f64in, double* Tout) {
    hipMemsetAsync(Msc, 0, 8, stream);
    if (f64in) {
      maxabs_k<double><<<256, blk, 0, stream>>>((const double*)Y, Msc, NN * DIM);
      sliceYT_k<double><<<dim3(5, 64), blk, 0, stream>>>((const double*)Y, Msc, Bpl);
    } else {
      maxabs_k<float><<<256, blk, 0, stream>>>((const float*)Y, Msc, NN * DIM);
      sliceYT_k<float><<<dim3(5, 64), blk, 0, stream>>>((const float*)Y, Msc, Bpl);
    }
    ozaki2b_k<<<dim3(3, 32, 10), blk, 0, stream>>>(Apl, Bpl, Iprt);
    reasm2_k<<<cdiv(NN * DIM, 256), blk, 0, stream>>>(Iprt, Msc, Tout, NN * DIM);
  };

  auto topk = [&](int k_keep, int* idx, double* vals) {
    bitonic_local_k<<<2, dim3(1024), 0, stream>>>(keys);
    bitonic_gphase_k<<<8, blk, 0, stream>>>(keys);
    bitonic_final_k<<<2, dim3(1024), 0, stream>>>(keys, k_keep, idx, vals);
  };

  // One-time conversions
  cvtA_bf16_k<<<cdiv(NN * NN / 4, 256), blk, 0, stream>>>(A, Abf, NN * NN);
  sliceA_k<<<cdiv(NN * NN / 4, 256), blk, 0, stream>>>(A, Apl);
  cvt32to64_k<<<cdiv(DIM * DIM, 256), blk, 0, stream>>>(w_start, Ws64,  DIM * DIM);
  cvt32to64_k<<<cdiv(DIM * DIM, 256), blk, 0, stream>>>(w_down0, Wd064, DIM * DIM);
  cvt32to64_k<<<cdiv(DIM * DIM, 256), blk, 0, stream>>>(w_down1, Wd164, DIM * DIM);
  transpose_bf16_k<<<dim3(5, 5),  blk, 0, stream>>>(w_bottom, wbT,  DIM, DIM);
  transpose_bf16_k<<<dim3(5, 5),  blk, 0, stream>>>(w_up0,    wu0T, DIM, DIM);
  transpose_bf16_k<<<dim3(5, 5),  blk, 0, stream>>>(w_up1,    wu1T, DIM, DIM);
  transpose_bf16_k<<<dim3(5, 10), blk, 0, stream>>>(w_end,    weT,  2 * DIM, DIM);

  // ---- down path: big A-GEMMs in exact-i8, feature GEMMs in f64 MFMA ----
  // 1) T = A @ X
  big_gemm(X, false, B1);
  // 2) X0 = relu(T @ w_start + b)  (+fused f32 out_x0)
  dmfma_k<double, 1, false><<<gd_sm, blk, 0, stream>>>(
      B1, Ws64, B2, b_start, nullptr, out_x0, NN, DIM, DIM, DIM, DIM, DIM);
  // 3) T = A @ X0
  big_gemm(B2, true, B1);
  // 4) Xd0 = relu(T @ w_down0 + b)  (+fused f32 Xd0f)
  dmfma_k<double, 1, false><<<gd_sm, blk, 0, stream>>>(
      B1, Wd064, B3, b_down0, nullptr, Xd0f, NN, DIM, DIM, DIM, DIM, DIM);
  // 5) pool0 scores -> sort -> idx0, vals0
  score_keys_k<<<NN, dim3(64), 0, stream>>>(B3, p_w0, p_b0, NN, keys);
  topk(KP0, idx0, vals0);
  // 6) Xp0: scattered f64 + compact bf16 (for pool_out)
  hipMemsetAsync(B2, 0, (size_t)NN * DIM * 8, stream);
  scatter64_k<<<cdiv(KP0 * DIM, 256), blk, 0, stream>>>(B3, idx0, vals0, idx0, B2, Pbf, KP0);
  // 7) T = A @ Xp0s ; Xd1 = relu(gather_idx0(T) @ w_down1 + b)  (+fused Xd1f)
  big_gemm(B2, true, B1);
  dmfma_k<double, 1, true><<<gd_smk0, blk, 0, stream>>>(
      B1, Wd164, B2, b_down1, idx0, Xd1f, KP0, DIM, DIM, DIM, DIM, DIM);
  // 8) pool1 scores -> idx1, vals1, idx01
  score_keys_k<<<NN, dim3(64), 0, stream>>>(B2, p_w1, p_b1, KP0, keys);
  topk(KP1, idx1, vals1);
  compose_k<<<cdiv(KP1, 256), blk, 0, stream>>>(idx0, idx1, idx01, KP1);

  // ---- up path, bf16 MFMA (big A-GEMMs: mfma2_k, split-K=4, klen=1024) ----
  // 9) Xb = relu(gather_idx01(A@Xp1s) @ w_bottom + b)
  hipMemsetAsync(Xs32, 0, (size_t)NN * DIM * 4, stream);
  scatter32_from64_k<<<cdiv(KP1 * DIM, 256), blk, 0, stream>>>(B2, idx1, vals1, idx01, Xs32, KP1);
  transpose_bf16_k<<<dim3(5, 64), blk, 0, stream>>>(Xs32, XbfT, NN, DIM);
  mfma2_k<<<dim3(3, 32, 4), blk, 0, stream>>>(Abf, XbfT, Pf, DIM, 1024, DIM);
  reduceb_k<<<cdiv(NN * DIM / 4, 256), blk, 0, stream>>>(Pf, Tbf, NN * DIM, 4, strd64);
  mfma_gemm_k<1, true, false><<<dim3(5, cdiv(KP1, 128), 1), blk, 0, stream>>>(
      Tbf, wbT, Xc, b_bottom, nullptr, idx01, KP1, DIM, DIM, DIM, DIM, DIM, 0);
  // 10) Xu = relu(gather_idx0(A@scatter_idx01(Xb)) @ w_up0 + b) + Xd1
  hipMemsetAsync(Xs32, 0, (size_t)NN * DIM * 4, stream);
  scatter32_k<<<cdiv(KP1 * DIM, 256), blk, 0, stream>>>(Xc, idx01, Xs32, KP1);
  transpose_bf16_k<<<dim3(5, 64), blk, 0, stream>>>(Xs32, XbfT, NN, DIM);
  mfma2_k<<<dim3(3, 32, 4), blk, 0, stream>>>(Abf, XbfT, Pf, DIM, 1024, DIM);
  reduceb_k<<<cdiv(NN * DIM / 4, 256), blk, 0, stream>>>(Pf, Tbf, NN * DIM, 4, strd64);
  mfma_gemm_k<2, true, false><<<dim3(5, cdiv(KP0, 128), 1), blk, 0, stream>>>(
      Tbf, wu0T, Xc, b_up0, Xd1f, idx0, KP0, DIM, DIM, DIM, DIM, DIM, DIM);
  // 11) Xu2 = relu(A@scatter_idx0(Xu) @ w_up1 + b) + Xd0  -> Xcat[:, :320]
  hipMemsetAsync(Xs32, 0, (size_t)NN * DIM * 4, stream);
  scatter32_k<<<cdiv(KP0 * DIM, 256), blk, 0, stream>>>(Xc, idx0, Xs32, KP0);
  transpose_bf16_k<<<dim3(5, 64), blk, 0, stream>>>(Xs32, XbfT, NN, DIM);
  mfma2_k<<<dim3(3, 32, 4), blk, 0, stream>>>(Abf, XbfT, Pf, DIM, 1024, DIM);
  reduceb_k<<<cdiv(NN * DIM / 4, 256), blk, 0, stream>>>(Pf, Tbf, NN * DIM, 4, strd64);
  mfma_gemm_k<2, false, false><<<dim3(5, 32, 1), blk, 0, stream>>>(
      Tbf, wu1T, Xcat, b_up1, Xd0f, nullptr, NN, DIM, DIM, DIM, DIM, 2 * DIM, DIM);
  copycols_k<<<cdiv(NN * DIM, 256), blk, 0, stream>>>(Xcat, out_x0);
  // 12) Xout = relu((A@Xcat) @ w_end + b_end)
  transpose_bf16_k<<<dim3(10, 64), blk, 0, stream>>>(Xcat, XbfT, NN, 2 * DIM);
  mfma2_k<<<dim3(5, 32, 4), blk, 0, stream>>>(Abf, XbfT, Pf, 2 * DIM, 1024, 2 * DIM);
  reduceb_k<<<cdiv(NN * 2 * DIM / 4, 256), blk, 0, stream>>>(
      Pf, Tbf, NN * 2 * DIM, 4, (size_t)NN * 2 * DIM);
  mfma_gemm_k<1, false, false><<<dim3(5, 32, 1), blk, 0, stream>>>(
      Tbf, weT, out_x, b_end, nullptr, nullptr, NN, DIM, 2 * DIM, 2 * DIM, 2 * DIM, DIM, 0);
  // 13) pool_out = Xp0 @ Xp0^T (both operands row-major-in-K), diag = 1
  mfma_gemm_k<0, false, false><<<dim3(cdiv(KP0, 64), cdiv(KP0, 128), 1), blk, 0, stream>>>(
      Pbf, Pbf, out_po, nullptr, nullptr, nullptr, KP0, KP0, DIM, DIM, DIM, KP0, 0);
  diag_k<<<cdiv(KP0, 256), blk, 0, stream>>>(out_po);
}